// Round 5
// baseline (1558.787 us; speedup 1.0000x reference)
//
#include <hip/hip_runtime.h>

#define Nn 50000
#define Rr 16
#define Dd 64
#define Fin 128
#define Ee 100000

typedef __attribute__((ext_vector_type(8))) short short8;
typedef __attribute__((ext_vector_type(4))) float f32x4;
typedef unsigned short ushort_t;

__device__ inline ushort_t f2bf(float x) {
  union { float f; unsigned u; } v; v.f = x;
  unsigned u = v.u;
  return (ushort_t)((u + 0x7FFFu + ((u >> 16) & 1u)) >> 16);  // RNE
}
__device__ inline float bf2f(ushort_t h) {
  union { unsigned u; float f; } v; v.u = ((unsigned)h) << 16; return v.f;
}

// ---------------- fused pre: init_gemm + convw + hist (independent work) ----
#define INIT_NB 12500              // 50000 rows / 4 per block
#define CONVW_NB 512               // 2*16*64*64 / 256 = 512 exactly
#define HIST_NBX 391               // ceil(100000/256)
__global__ __launch_bounds__(256) void pre_k(const float* __restrict__ x,
                                             const float* __restrict__ w,
                                             ushort_t* __restrict__ emb0,
                                             const float* __restrict__ rel,
                                             ushort_t* __restrict__ wbf,
                                             const int* __restrict__ erow,
                                             int* __restrict__ cnt) {
  int b = blockIdx.x;
  if (b < INIT_NB) {
    int wave = threadIdx.x >> 6, lane = threadIdx.x & 63;
    int row = b * 4 + wave;
    const float* xr = x + (long)row * Fin;
    float acc = 0.f;
#pragma unroll 8
    for (int k = 0; k < Fin; ++k)
      acc = fmaf(xr[k], w[k * Dd + lane], acc);  // xr[k] wave-uniform
    emb0[(unsigned)row * Dd + lane] = f2bf(acc);
  } else if (b < INIT_NB + CONVW_NB) {
    int i = (b - INIT_NB) * 256 + threadIdx.x;
    wbf[i] = f2bf(rel[i]);
  } else {
    int bb = b - INIT_NB - CONVW_NB;
    int r = bb / HIST_NBX;
    int e = (bb % HIST_NBX) * 256 + threadIdx.x;
    if (e < Ee) atomicAdd(&cnt[erow[r * Ee + e]], 1);
  }
}

// ---------------- parallel scan, 3 kernels ----------------
#define SCAN_NB ((Nn + 255) / 256)  // 196
__global__ __launch_bounds__(256) void scan1_k(const int* __restrict__ cnt,
                                               int* __restrict__ bsum) {
  __shared__ int ls[256];
  int t = threadIdx.x, i = blockIdx.x * 256 + t;
  int v = (i < Nn) ? cnt[i] : 0;
  ls[t] = v;
  __syncthreads();
  for (int off = 128; off >= 1; off >>= 1) {
    if (t < off) ls[t] += ls[t + off];
    __syncthreads();
  }
  if (t == 0) bsum[blockIdx.x] = ls[0];
}

__global__ __launch_bounds__(256) void scan2_k(int* __restrict__ bsum) {
  __shared__ int ls[256];
  int t = threadIdx.x;
  int v = (t < SCAN_NB) ? bsum[t] : 0;
  ls[t] = v;
  __syncthreads();
  for (int off = 1; off < 256; off <<= 1) {
    int x = (t >= off) ? ls[t - off] : 0;
    __syncthreads();
    ls[t] += x;
    __syncthreads();
  }
  if (t < SCAN_NB) bsum[t] = ls[t] - v;  // exclusive
}

__global__ __launch_bounds__(256) void scan3_k(int* __restrict__ cnt,
                                               const int* __restrict__ bsum,
                                               int* __restrict__ offs) {
  __shared__ int ls[256];
  int t = threadIdx.x, i = blockIdx.x * 256 + t;
  int v = (i < Nn) ? cnt[i] : 0;
  ls[t] = v;
  __syncthreads();
  for (int off = 1; off < 256; off <<= 1) {
    int x = (t >= off) ? ls[t - off] : 0;
    __syncthreads();
    ls[t] += x;
    __syncthreads();
  }
  int excl = ls[t] - v + bsum[blockIdx.x];
  if (i < Nn) {
    offs[i] = excl;
    cnt[i] = excl;  // becomes cursor
  }
  if (i == Nn - 1) offs[Nn] = Rr * Ee;
}

__global__ __launch_bounds__(256) void scatter_k(const int* __restrict__ erow,
                                                 const int* __restrict__ ecol,
                                                 const float* __restrict__ ev,
                                                 int* __restrict__ cursor,
                                                 uint2* __restrict__ ed) {
  int e = blockIdx.x * 256 + threadIdx.x;
  int r = blockIdx.y;
  if (e >= Ee) return;
  long idx = (long)r * Ee + e;
  int row = erow[idx];
  int pos = atomicAdd(&cursor[row], 1);
  ed[pos] = make_uint2(((unsigned)r << 16) | (unsigned)ecol[idx],
                       __float_as_uint(ev[idx]));
}

// ---------------- gather2: Z[row][rel][d] = seg-sum val*emb[col][d] ---------
// Wave per row; rel-demux via 4KB wave-private LDS f32 buffer (ds_add_f32,
// lane=d -> conflict-free). Row's edge list is contiguous; 8-unrolled MLP.
__global__ __launch_bounds__(256) void gather2_k(const ushort_t* __restrict__ emb,
                                                 const int* __restrict__ offs,
                                                 const uint2* __restrict__ ed,
                                                 ushort_t* __restrict__ Z) {
  __shared__ float zb[4][Rr * Dd];  // 16 KB
  int wave = threadIdx.x >> 6, lane = threadIdx.x & 63;
  int row = blockIdx.x * 4 + wave;
  if (row >= Nn) return;
  float* zw = zb[wave];
#pragma unroll
  for (int r = 0; r < Rr; ++r) zw[r * Dd + lane] = 0.f;

  int s = offs[row], e = offs[row + 1];
  int i = s;
  const int e8 = s + ((e - s) & ~7);
  for (; i < e8; i += 8) {
    uint2 q[8];
#pragma unroll
    for (int j = 0; j < 8; ++j) q[j] = ed[i + j];
    float y[8];
#pragma unroll
    for (int j = 0; j < 8; ++j)
      y[j] = bf2f(emb[(q[j].x & 0xFFFFu) * 64u + lane]);
#pragma unroll
    for (int j = 0; j < 8; ++j)
      atomicAdd(&zw[(q[j].x >> 16) * 64u + lane],
                __uint_as_float(q[j].y) * y[j]);
  }
  for (; i < e; ++i) {
    uint2 q = ed[i];
    atomicAdd(&zw[(q.x >> 16) * 64u + lane],
              __uint_as_float(q.y) * bf2f(emb[(q.x & 0xFFFFu) * 64u + lane]));
  }
  // flush: row's Z slice is contiguous 2KB -> fully coalesced
  ushort_t* zrow = Z + (size_t)row * (Rr * Dd);
#pragma unroll
  for (int r = 0; r < Rr; ++r)
    zrow[r * Dd + lane] = f2bf(zw[r * Dd + lane]);
}

// ---------------- zgemm: out[row] = relu(sum_r Z[row][r] @ W_r^T) -----------
// Wave per 16-row tile; acc persists across all 16 rels (register blockdiag).
__global__ __launch_bounds__(256) void zgemm_k(const ushort_t* __restrict__ Z,
                                               const ushort_t* __restrict__ wl,
                                               ushort_t* __restrict__ embout,
                                               float* __restrict__ finout,
                                               int fin) {
  int wave = threadIdx.x >> 6, lane = threadIdx.x & 63;
  int nt = lane & 15, quad = lane >> 4;
  int tile = blockIdx.x * 4 + wave;
  if (tile >= Nn / 16) return;

  const ushort_t* za = Z + (size_t)(tile * 16 + nt) * (Rr * Dd) + quad * 8;
  f32x4 acc[4];
#pragma unroll
  for (int dt = 0; dt < 4; ++dt) acc[dt] = (f32x4){0.f, 0.f, 0.f, 0.f};

  for (int r = 0; r < Rr; ++r) {
    short8 a0 = *(const short8*)(za + r * Dd);
    short8 a1 = *(const short8*)(za + r * Dd + 32);
#pragma unroll
    for (int dt = 0; dt < 4; ++dt) {
      const ushort_t* bp = wl + ((unsigned)r * Dd + dt * 16 + nt) * Dd + quad * 8;
      short8 b0 = *(const short8*)(bp);
      short8 b1 = *(const short8*)(bp + 32);
      acc[dt] = __builtin_amdgcn_mfma_f32_16x16x32_bf16(a0, b0, acc[dt], 0, 0, 0);
      acc[dt] = __builtin_amdgcn_mfma_f32_16x16x32_bf16(a1, b1, acc[dt], 0, 0, 0);
    }
  }

  // C layout: D[m=quad*4+reg][col=dt*16+nt]
  if (!fin) {
#pragma unroll
    for (int dt = 0; dt < 4; ++dt)
#pragma unroll
      for (int reg = 0; reg < 4; ++reg) {
        int row = tile * 16 + quad * 4 + reg;
        embout[(unsigned)row * 64u + dt * 16 + nt] = f2bf(fmaxf(acc[dt][reg], 0.f));
      }
  } else {
    float v[4][4];
#pragma unroll
    for (int dt = 0; dt < 4; ++dt)
#pragma unroll
      for (int reg = 0; reg < 4; ++reg) v[dt][reg] = fmaxf(acc[dt][reg], 0.f);
#pragma unroll
    for (int reg = 0; reg < 4; ++reg) {
      float ss = 0.f;
#pragma unroll
      for (int dt = 0; dt < 4; ++dt) ss = fmaf(v[dt][reg], v[dt][reg], ss);
#pragma unroll
      for (int off = 8; off >= 1; off >>= 1)
        ss += __shfl_xor(ss, off, 64);  // reduce over nt (quad bits preserved)
      float sc = 1.f / fmaxf(sqrtf(ss), 1e-12f);
      int row = tile * 16 + quad * 4 + reg;
#pragma unroll
      for (int dt = 0; dt < 4; ++dt)
        finout[(unsigned)row * 64u + dt * 16 + nt] = v[dt][reg] * sc;
    }
  }
}

extern "C" void kernel_launch(void* const* d_in, const int* in_sizes, int n_in,
                              void* d_out, int out_size, void* d_ws, size_t ws_size,
                              hipStream_t stream) {
  const float* x   = (const float*)d_in[0];
  const float* ent = (const float*)d_in[1];
  const float* rel = (const float*)d_in[2];
  const int* erow  = (const int*)d_in[3];
  const int* ecol  = (const int*)d_in[4];
  const float* ev  = (const float*)d_in[5];
  float* out = (float*)d_out;

  char* p = (char*)d_ws;
  ushort_t* emb_a = (ushort_t*)p;  p += (size_t)Nn * Dd * 2;           // 6.4 MB
  ushort_t* emb_b = (ushort_t*)p;  p += (size_t)Nn * Dd * 2;           // 6.4 MB
  ushort_t* wbf   = (ushort_t*)p;  p += (size_t)2 * Rr * Dd * Dd * 2;  // 256 KB
  ushort_t* Z     = (ushort_t*)p;  p += (size_t)Nn * Rr * Dd * 2;      // 102.4 MB
  uint2* ed       = (uint2*)p;     p += (size_t)Rr * Ee * 8;           // 12.8 MB
  int* offs       = (int*)p;       p += (size_t)(Nn + 4) * 4;
  int* cnt        = (int*)p;       p += (size_t)Nn * 4;
  int* bsum       = (int*)p;       p += 256 * 4;

  hipMemsetAsync(cnt, 0, (size_t)Nn * 4, stream);
  pre_k<<<INIT_NB + CONVW_NB + HIST_NBX * Rr, 256, 0, stream>>>(
      x, ent, emb_a, rel, wbf, erow, cnt);
  scan1_k<<<SCAN_NB, 256, 0, stream>>>(cnt, bsum);
  scan2_k<<<1, 256, 0, stream>>>(bsum);
  scan3_k<<<SCAN_NB, 256, 0, stream>>>(cnt, bsum, offs);
  scatter_k<<<dim3((Ee + 255) / 256, Rr), 256, 0, stream>>>(erow, ecol, ev, cnt, ed);

  // layer 1
  gather2_k<<<(Nn + 3) / 4, 256, 0, stream>>>(emb_a, offs, ed, Z);
  zgemm_k<<<(Nn / 16 + 3) / 4, 256, 0, stream>>>(Z, wbf, emb_b, nullptr, 0);
  // layer 2 (+ relu + L2 normalize fused)
  gather2_k<<<(Nn + 3) / 4, 256, 0, stream>>>(emb_b, offs, ed, Z);
  zgemm_k<<<(Nn / 16 + 3) / 4, 256, 0, stream>>>(Z, wbf + (size_t)Rr * Dd * Dd,
                                                 nullptr, out, 1);
}

// Round 6
// 706.042 us; speedup vs baseline: 2.2078x; 2.2078x over previous
//
#include <hip/hip_runtime.h>

#define Nn 50000
#define Rr 16
#define Dd 64
#define Fin 128
#define Ee 100000
#define NB2 (Nn * Rr)  // 800000 (row,rel) bins

typedef __attribute__((ext_vector_type(8))) short short8;
typedef __attribute__((ext_vector_type(4))) float f32x4;
typedef unsigned short ushort_t;

__device__ inline ushort_t f2bf(float x) {
  union { float f; unsigned u; } v; v.f = x;
  unsigned u = v.u;
  return (ushort_t)((u + 0x7FFFu + ((u >> 16) & 1u)) >> 16);  // RNE
}
__device__ inline float bf2f(ushort_t h) {
  union { unsigned u; float f; } v; v.u = ((unsigned)h) << 16; return v.f;
}

// ---------------- fused pre: init_gemm + convw + hist (independent work) ----
#define INIT_NB 12500              // 50000 rows / 4 per block
#define CONVW_NB 512               // 2*16*64*64 / 256
#define HIST_NBX 391               // ceil(100000/256)
__global__ __launch_bounds__(256) void pre_k(const float* __restrict__ x,
                                             const float* __restrict__ w,
                                             ushort_t* __restrict__ emb0,
                                             const float* __restrict__ rel,
                                             ushort_t* __restrict__ wbf,
                                             const int* __restrict__ erow,
                                             int* __restrict__ cnt2) {
  int b = blockIdx.x;
  if (b < INIT_NB) {
    int wave = threadIdx.x >> 6, lane = threadIdx.x & 63;
    int row = b * 4 + wave;
    const float* xr = x + (long)row * Fin;
    float acc = 0.f;
#pragma unroll 8
    for (int k = 0; k < Fin; ++k)
      acc = fmaf(xr[k], w[k * Dd + lane], acc);  // xr[k] wave-uniform
    emb0[(unsigned)row * Dd + lane] = f2bf(acc);
  } else if (b < INIT_NB + CONVW_NB) {
    int i = (b - INIT_NB) * 256 + threadIdx.x;
    wbf[i] = f2bf(rel[i]);
  } else {
    int bb = b - INIT_NB - CONVW_NB;
    int r = bb / HIST_NBX;
    int e = (bb % HIST_NBX) * 256 + threadIdx.x;
    if (e < Ee) atomicAdd(&cnt2[erow[r * Ee + e] * Rr + r], 1);
  }
}

// ---------------- parallel scan over 800000 bins, 3 kernels ----------------
#define SCAN_NBX 3125  // 800000 / 256 exact
__global__ __launch_bounds__(256) void scan1_k(const int* __restrict__ cnt,
                                               int* __restrict__ bsum) {
  __shared__ int ls[256];
  int t = threadIdx.x;
  ls[t] = cnt[blockIdx.x * 256 + t];
  __syncthreads();
  for (int off = 128; off >= 1; off >>= 1) {
    if (t < off) ls[t] += ls[t + off];
    __syncthreads();
  }
  if (t == 0) bsum[blockIdx.x] = ls[0];
}

// 1 block, 1024 threads, 4 items each: exclusive scan of 3125 partials
__global__ __launch_bounds__(1024) void scan2_k(int* __restrict__ bsum) {
  __shared__ int ls[1024];
  int t = threadIdx.x;
  int v[4], s = 0;
#pragma unroll
  for (int j = 0; j < 4; ++j) {
    int idx = t * 4 + j;
    v[j] = (idx < SCAN_NBX) ? bsum[idx] : 0;
    s += v[j];
  }
  ls[t] = s;
  __syncthreads();
  for (int off = 1; off < 1024; off <<= 1) {
    int x = (t >= off) ? ls[t - off] : 0;
    __syncthreads();
    ls[t] += x;
    __syncthreads();
  }
  int run = ls[t] - s;  // exclusive
#pragma unroll
  for (int j = 0; j < 4; ++j) {
    int idx = t * 4 + j;
    if (idx < SCAN_NBX) { bsum[idx] = run; run += v[j]; }
  }
}

__global__ __launch_bounds__(256) void scan3_k(int* __restrict__ cnt,
                                               const int* __restrict__ bsum,
                                               int* __restrict__ offs) {
  __shared__ int ls[256];
  int t = threadIdx.x, i = blockIdx.x * 256 + t;
  int v = cnt[i];
  ls[t] = v;
  __syncthreads();
  for (int off = 1; off < 256; off <<= 1) {
    int x = (t >= off) ? ls[t - off] : 0;
    __syncthreads();
    ls[t] += x;
    __syncthreads();
  }
  int excl = ls[t] - v + bsum[blockIdx.x];
  offs[i] = excl;
  cnt[i] = excl;  // becomes cursor
  if (i == NB2 - 1) offs[NB2] = Rr * Ee;
}

// ---------------- scatter into (row,rel)-sorted order; ed = (col, val) -----
__global__ __launch_bounds__(256) void scatter_k(const int* __restrict__ erow,
                                                 const int* __restrict__ ecol,
                                                 const float* __restrict__ ev,
                                                 int* __restrict__ cursor,
                                                 uint2* __restrict__ ed) {
  int e = blockIdx.x * 256 + threadIdx.x;
  int r = blockIdx.y;
  if (e >= Ee) return;
  long idx = (long)r * Ee + e;
  int bin = erow[idx] * Rr + r;
  int pos = atomicAdd(&cursor[bin], 1);
  ed[pos] = make_uint2((unsigned)ecol[idx], __float_as_uint(ev[idx]));
}

// ---------------- gather3: Z[row][r][d] = sum over segment (register acc) ---
// Wave per row; segment bounds from offs2 via one lane-load + shfl.
// No LDS, no atomics; per rel one coalesced 128B store.
__global__ __launch_bounds__(256) void gather3_k(const ushort_t* __restrict__ emb,
                                                 const int* __restrict__ offs2,
                                                 const uint2* __restrict__ ed,
                                                 ushort_t* __restrict__ Z) {
  int wave = threadIdx.x >> 6, lane = threadIdx.x & 63;
  int row = blockIdx.x * 4 + wave;
  if (row >= Nn) return;
  int off_l = (lane < 17) ? offs2[row * Rr + lane] : 0;
  ushort_t* zrow = Z + (size_t)row * (Rr * Dd);
#pragma unroll
  for (int r = 0; r < Rr; ++r) {
    int s = __shfl(off_l, r, 64), e = __shfl(off_l, r + 1, 64);
    float acc0 = 0.f, acc1 = 0.f;
    int i = s;
    for (; i + 1 < e; i += 2) {
      uint2 q0 = ed[i], q1 = ed[i + 1];
      float y0 = bf2f(emb[q0.x * 64u + lane]);
      float y1 = bf2f(emb[q1.x * 64u + lane]);
      acc0 = fmaf(__uint_as_float(q0.y), y0, acc0);
      acc1 = fmaf(__uint_as_float(q1.y), y1, acc1);
    }
    if (i < e) {
      uint2 q = ed[i];
      acc0 = fmaf(__uint_as_float(q.y), bf2f(emb[q.x * 64u + lane]), acc0);
    }
    zrow[r * Dd + lane] = f2bf(acc0 + acc1);
  }
}

// ---------------- zgemm: out[row] = relu(sum_r Z[row][r] @ W_r^T) -----------
__global__ __launch_bounds__(256) void zgemm_k(const ushort_t* __restrict__ Z,
                                               const ushort_t* __restrict__ wl,
                                               ushort_t* __restrict__ embout,
                                               float* __restrict__ finout,
                                               int fin) {
  int wave = threadIdx.x >> 6, lane = threadIdx.x & 63;
  int nt = lane & 15, quad = lane >> 4;
  int tile = blockIdx.x * 4 + wave;
  if (tile >= Nn / 16) return;

  const ushort_t* za = Z + (size_t)(tile * 16 + nt) * (Rr * Dd) + quad * 8;
  f32x4 acc[4];
#pragma unroll
  for (int dt = 0; dt < 4; ++dt) acc[dt] = (f32x4){0.f, 0.f, 0.f, 0.f};

  for (int r = 0; r < Rr; ++r) {
    short8 a0 = *(const short8*)(za + r * Dd);
    short8 a1 = *(const short8*)(za + r * Dd + 32);
#pragma unroll
    for (int dt = 0; dt < 4; ++dt) {
      const ushort_t* bp = wl + ((unsigned)r * Dd + dt * 16 + nt) * Dd + quad * 8;
      short8 b0 = *(const short8*)(bp);
      short8 b1 = *(const short8*)(bp + 32);
      acc[dt] = __builtin_amdgcn_mfma_f32_16x16x32_bf16(a0, b0, acc[dt], 0, 0, 0);
      acc[dt] = __builtin_amdgcn_mfma_f32_16x16x32_bf16(a1, b1, acc[dt], 0, 0, 0);
    }
  }

  // C layout: D[m=quad*4+reg][col=dt*16+nt]
  if (!fin) {
#pragma unroll
    for (int dt = 0; dt < 4; ++dt)
#pragma unroll
      for (int reg = 0; reg < 4; ++reg) {
        int row = tile * 16 + quad * 4 + reg;
        embout[(unsigned)row * 64u + dt * 16 + nt] = f2bf(fmaxf(acc[dt][reg], 0.f));
      }
  } else {
    float v[4][4];
#pragma unroll
    for (int dt = 0; dt < 4; ++dt)
#pragma unroll
      for (int reg = 0; reg < 4; ++reg) v[dt][reg] = fmaxf(acc[dt][reg], 0.f);
#pragma unroll
    for (int reg = 0; reg < 4; ++reg) {
      float ss = 0.f;
#pragma unroll
      for (int dt = 0; dt < 4; ++dt) ss = fmaf(v[dt][reg], v[dt][reg], ss);
#pragma unroll
      for (int off = 8; off >= 1; off >>= 1)
        ss += __shfl_xor(ss, off, 64);  // reduce over nt
      float sc = 1.f / fmaxf(sqrtf(ss), 1e-12f);
      int row = tile * 16 + quad * 4 + reg;
#pragma unroll
      for (int dt = 0; dt < 4; ++dt)
        finout[(unsigned)row * 64u + dt * 16 + nt] = v[dt][reg] * sc;
    }
  }
}

extern "C" void kernel_launch(void* const* d_in, const int* in_sizes, int n_in,
                              void* d_out, int out_size, void* d_ws, size_t ws_size,
                              hipStream_t stream) {
  const float* x   = (const float*)d_in[0];
  const float* ent = (const float*)d_in[1];
  const float* rel = (const float*)d_in[2];
  const int* erow  = (const int*)d_in[3];
  const int* ecol  = (const int*)d_in[4];
  const float* ev  = (const float*)d_in[5];
  float* out = (float*)d_out;

  char* p = (char*)d_ws;
  ushort_t* emb_a = (ushort_t*)p;  p += (size_t)Nn * Dd * 2;           // 6.4 MB
  ushort_t* emb_b = (ushort_t*)p;  p += (size_t)Nn * Dd * 2;           // 6.4 MB
  ushort_t* wbf   = (ushort_t*)p;  p += (size_t)2 * Rr * Dd * Dd * 2;  // 256 KB
  ushort_t* Z     = (ushort_t*)p;  p += (size_t)Nn * Rr * Dd * 2;      // 102.4 MB
  uint2* ed       = (uint2*)p;     p += (size_t)Rr * Ee * 8;           // 12.8 MB
  int* offs2      = (int*)p;       p += (size_t)(NB2 + 4) * 4;         // 3.2 MB
  int* cnt2       = (int*)p;       p += (size_t)NB2 * 4;               // 3.2 MB
  int* bsum       = (int*)p;       p += (size_t)SCAN_NBX * 4;

  hipMemsetAsync(cnt2, 0, (size_t)NB2 * 4, stream);
  pre_k<<<INIT_NB + CONVW_NB + HIST_NBX * Rr, 256, 0, stream>>>(
      x, ent, emb_a, rel, wbf, erow, cnt2);
  scan1_k<<<SCAN_NBX, 256, 0, stream>>>(cnt2, bsum);
  scan2_k<<<1, 1024, 0, stream>>>(bsum);
  scan3_k<<<SCAN_NBX, 256, 0, stream>>>(cnt2, bsum, offs2);
  scatter_k<<<dim3((Ee + 255) / 256, Rr), 256, 0, stream>>>(erow, ecol, ev, cnt2, ed);

  // layer 1
  gather3_k<<<(Nn + 3) / 4, 256, 0, stream>>>(emb_a, offs2, ed, Z);
  zgemm_k<<<(Nn / 16 + 3) / 4, 256, 0, stream>>>(Z, wbf, emb_b, nullptr, 0);
  // layer 2 (+ relu + L2 normalize fused)
  gather3_k<<<(Nn + 3) / 4, 256, 0, stream>>>(emb_b, offs2, ed, Z);
  zgemm_k<<<(Nn / 16 + 3) / 4, 256, 0, stream>>>(Z, wbf + (size_t)Rr * Dd * Dd,
                                                 nullptr, out, 1);
}

// Round 7
// 666.429 us; speedup vs baseline: 2.3390x; 1.0594x over previous
//
#include <hip/hip_runtime.h>

#define Nn 50000
#define Rr 16
#define Dd 64
#define Fin 128
#define Ee 100000
#define NB2 (Nn * Rr)  // 800000 (row,rel) bins

typedef __attribute__((ext_vector_type(8))) short short8;
typedef __attribute__((ext_vector_type(4))) float f32x4;
typedef unsigned short ushort_t;

__device__ inline ushort_t f2bf(float x) {
  union { float f; unsigned u; } v; v.f = x;
  unsigned u = v.u;
  return (ushort_t)((u + 0x7FFFu + ((u >> 16) & 1u)) >> 16);  // RNE
}
__device__ inline float bf2f(ushort_t h) {
  union { unsigned u; float f; } v; v.u = ((unsigned)h) << 16; return v.f;
}

// ---------------- fused pre: MFMA init_gemm + convw + hist ----------------
// init: emb0[16-row tile] = x_tile[16x128] @ ent[128x64], 16 MFMAs/wave.
#define INIT_TILES 3125            // 50000/16
#define INIT_NB 782                // ceil(3125/4)
#define CONVW_NB 512               // 2*16*64*64 / 256
#define HIST_NBX 391               // ceil(100000/256)
__global__ __launch_bounds__(256) void pre_k(const float* __restrict__ x,
                                             const float* __restrict__ ent,
                                             ushort_t* __restrict__ emb0,
                                             const float* __restrict__ rel,
                                             ushort_t* __restrict__ wbf,
                                             const int* __restrict__ erow,
                                             int* __restrict__ cnt2) {
  int b = blockIdx.x;
  if (b < INIT_NB) {
    int wave = threadIdx.x >> 6, lane = threadIdx.x & 63;
    int nt = lane & 15, quad = lane >> 4;
    int tile = b * 4 + wave;
    if (tile >= INIT_TILES) return;
    // A frags: x[tile*16+nt][ks*32+quad*8 .. +8), f32 -> bf16
    const float* xr = x + ((long)tile * 16 + nt) * Fin + quad * 8;
    short8 afrag[4];
#pragma unroll
    for (int ks = 0; ks < 4; ++ks) {
      float4 p0 = *(const float4*)(xr + ks * 32);
      float4 p1 = *(const float4*)(xr + ks * 32 + 4);
      short8 a;
      a[0] = (short)f2bf(p0.x); a[1] = (short)f2bf(p0.y);
      a[2] = (short)f2bf(p0.z); a[3] = (short)f2bf(p0.w);
      a[4] = (short)f2bf(p1.x); a[5] = (short)f2bf(p1.y);
      a[6] = (short)f2bf(p1.z); a[7] = (short)f2bf(p1.w);
      afrag[ks] = a;
    }
    f32x4 acc[4];
#pragma unroll
    for (int dt = 0; dt < 4; ++dt) acc[dt] = (f32x4){0.f, 0.f, 0.f, 0.f};
#pragma unroll
    for (int ks = 0; ks < 4; ++ks) {
#pragma unroll
      for (int dt = 0; dt < 4; ++dt) {
        // B[k][n] = ent[k][dt*16+nt], k = ks*32+quad*8+j
        short8 bfr;
#pragma unroll
        for (int j = 0; j < 8; ++j)
          bfr[j] = (short)f2bf(ent[(unsigned)(ks * 32 + quad * 8 + j) * Dd + dt * 16 + nt]);
        acc[dt] = __builtin_amdgcn_mfma_f32_16x16x32_bf16(afrag[ks], bfr, acc[dt], 0, 0, 0);
      }
    }
#pragma unroll
    for (int dt = 0; dt < 4; ++dt)
#pragma unroll
      for (int reg = 0; reg < 4; ++reg) {
        int row = tile * 16 + quad * 4 + reg;
        emb0[(unsigned)row * Dd + dt * 16 + nt] = f2bf(acc[dt][reg]);
      }
  } else if (b < INIT_NB + CONVW_NB) {
    int i = (b - INIT_NB) * 256 + threadIdx.x;
    wbf[i] = f2bf(rel[i]);
  } else {
    int bb = b - INIT_NB - CONVW_NB;
    int r = bb / HIST_NBX;
    int e = (bb % HIST_NBX) * 256 + threadIdx.x;
    if (e < Ee) atomicAdd(&cnt2[erow[r * Ee + e] * Rr + r], 1);
  }
}

// ---------------- parallel scan over 800000 bins, 3 kernels ----------------
#define SCAN_NBX 3125  // 800000 / 256 exact
__global__ __launch_bounds__(256) void scan1_k(const int* __restrict__ cnt,
                                               int* __restrict__ bsum) {
  __shared__ int ls[256];
  int t = threadIdx.x;
  ls[t] = cnt[blockIdx.x * 256 + t];
  __syncthreads();
  for (int off = 128; off >= 1; off >>= 1) {
    if (t < off) ls[t] += ls[t + off];
    __syncthreads();
  }
  if (t == 0) bsum[blockIdx.x] = ls[0];
}

__global__ __launch_bounds__(1024) void scan2_k(int* __restrict__ bsum) {
  __shared__ int ls[1024];
  int t = threadIdx.x;
  int v[4], s = 0;
#pragma unroll
  for (int j = 0; j < 4; ++j) {
    int idx = t * 4 + j;
    v[j] = (idx < SCAN_NBX) ? bsum[idx] : 0;
    s += v[j];
  }
  ls[t] = s;
  __syncthreads();
  for (int off = 1; off < 1024; off <<= 1) {
    int x = (t >= off) ? ls[t - off] : 0;
    __syncthreads();
    ls[t] += x;
    __syncthreads();
  }
  int run = ls[t] - s;  // exclusive
#pragma unroll
  for (int j = 0; j < 4; ++j) {
    int idx = t * 4 + j;
    if (idx < SCAN_NBX) { bsum[idx] = run; run += v[j]; }
  }
}

__global__ __launch_bounds__(256) void scan3_k(int* __restrict__ cnt,
                                               const int* __restrict__ bsum,
                                               int* __restrict__ offs) {
  __shared__ int ls[256];
  int t = threadIdx.x, i = blockIdx.x * 256 + t;
  int v = cnt[i];
  ls[t] = v;
  __syncthreads();
  for (int off = 1; off < 256; off <<= 1) {
    int x = (t >= off) ? ls[t - off] : 0;
    __syncthreads();
    ls[t] += x;
    __syncthreads();
  }
  int excl = ls[t] - v + bsum[blockIdx.x];
  offs[i] = excl;
  cnt[i] = excl;  // becomes cursor
  if (i == NB2 - 1) offs[NB2] = Rr * Ee;
}

// ------- scatter into (row,rel)-sorted order; ed = (val_bf16<<16 | col) -----
__global__ __launch_bounds__(256) void scatter_k(const int* __restrict__ erow,
                                                 const int* __restrict__ ecol,
                                                 const float* __restrict__ ev,
                                                 int* __restrict__ cursor,
                                                 unsigned* __restrict__ ed) {
  int e = blockIdx.x * 256 + threadIdx.x;
  int r = blockIdx.y;
  if (e >= Ee) return;
  long idx = (long)r * Ee + e;
  int bin = erow[idx] * Rr + r;
  int pos = atomicAdd(&cursor[bin], 1);
  unsigned vb = f2bf(ev[idx]);
  ed[pos] = (vb << 16) | (unsigned)ecol[idx];
}

// ---------------- gather3: Z[row][r][d] = sum over segment (register acc) ---
__global__ __launch_bounds__(256) void gather3_k(const ushort_t* __restrict__ emb,
                                                 const int* __restrict__ offs2,
                                                 const unsigned* __restrict__ ed,
                                                 ushort_t* __restrict__ Z) {
  int wave = threadIdx.x >> 6, lane = threadIdx.x & 63;
  int row = blockIdx.x * 4 + wave;
  if (row >= Nn) return;
  int off_l = (lane < 17) ? offs2[row * Rr + lane] : 0;
  ushort_t* zrow = Z + (size_t)row * (Rr * Dd);
#pragma unroll
  for (int r = 0; r < Rr; ++r) {
    int s = __shfl(off_l, r, 64), e = __shfl(off_l, r + 1, 64);
    float acc0 = 0.f, acc1 = 0.f;
    int i = s;
    for (; i + 1 < e; i += 2) {
      unsigned q0 = ed[i], q1 = ed[i + 1];
      float y0 = bf2f(emb[(q0 & 0xFFFFu) * 64u + lane]);
      float y1 = bf2f(emb[(q1 & 0xFFFFu) * 64u + lane]);
      acc0 = fmaf(__uint_as_float(q0 & 0xFFFF0000u), y0, acc0);
      acc1 = fmaf(__uint_as_float(q1 & 0xFFFF0000u), y1, acc1);
    }
    if (i < e) {
      unsigned q = ed[i];
      acc0 = fmaf(__uint_as_float(q & 0xFFFF0000u),
                  bf2f(emb[(q & 0xFFFFu) * 64u + lane]), acc0);
    }
    zrow[r * Dd + lane] = f2bf(acc0 + acc1);
  }
}

// ---------------- zgemm: out[row] = relu(sum_r Z[row][r] @ W_r^T) -----------
__global__ __launch_bounds__(256) void zgemm_k(const ushort_t* __restrict__ Z,
                                               const ushort_t* __restrict__ wl,
                                               ushort_t* __restrict__ embout,
                                               float* __restrict__ finout,
                                               int fin) {
  int wave = threadIdx.x >> 6, lane = threadIdx.x & 63;
  int nt = lane & 15, quad = lane >> 4;
  int tile = blockIdx.x * 4 + wave;
  if (tile >= Nn / 16) return;

  const ushort_t* za = Z + (size_t)(tile * 16 + nt) * (Rr * Dd) + quad * 8;
  f32x4 acc[4];
#pragma unroll
  for (int dt = 0; dt < 4; ++dt) acc[dt] = (f32x4){0.f, 0.f, 0.f, 0.f};

  for (int r = 0; r < Rr; ++r) {
    short8 a0 = *(const short8*)(za + r * Dd);
    short8 a1 = *(const short8*)(za + r * Dd + 32);
#pragma unroll
    for (int dt = 0; dt < 4; ++dt) {
      const ushort_t* bp = wl + ((unsigned)r * Dd + dt * 16 + nt) * Dd + quad * 8;
      short8 b0 = *(const short8*)(bp);
      short8 b1 = *(const short8*)(bp + 32);
      acc[dt] = __builtin_amdgcn_mfma_f32_16x16x32_bf16(a0, b0, acc[dt], 0, 0, 0);
      acc[dt] = __builtin_amdgcn_mfma_f32_16x16x32_bf16(a1, b1, acc[dt], 0, 0, 0);
    }
  }

  if (!fin) {
#pragma unroll
    for (int dt = 0; dt < 4; ++dt)
#pragma unroll
      for (int reg = 0; reg < 4; ++reg) {
        int row = tile * 16 + quad * 4 + reg;
        embout[(unsigned)row * 64u + dt * 16 + nt] = f2bf(fmaxf(acc[dt][reg], 0.f));
      }
  } else {
    float v[4][4];
#pragma unroll
    for (int dt = 0; dt < 4; ++dt)
#pragma unroll
      for (int reg = 0; reg < 4; ++reg) v[dt][reg] = fmaxf(acc[dt][reg], 0.f);
#pragma unroll
    for (int reg = 0; reg < 4; ++reg) {
      float ss = 0.f;
#pragma unroll
      for (int dt = 0; dt < 4; ++dt) ss = fmaf(v[dt][reg], v[dt][reg], ss);
#pragma unroll
      for (int off = 8; off >= 1; off >>= 1)
        ss += __shfl_xor(ss, off, 64);  // reduce over nt
      float sc = 1.f / fmaxf(sqrtf(ss), 1e-12f);
      int row = tile * 16 + quad * 4 + reg;
#pragma unroll
      for (int dt = 0; dt < 4; ++dt)
        finout[(unsigned)row * 64u + dt * 16 + nt] = v[dt][reg] * sc;
    }
  }
}

extern "C" void kernel_launch(void* const* d_in, const int* in_sizes, int n_in,
                              void* d_out, int out_size, void* d_ws, size_t ws_size,
                              hipStream_t stream) {
  const float* x   = (const float*)d_in[0];
  const float* ent = (const float*)d_in[1];
  const float* rel = (const float*)d_in[2];
  const int* erow  = (const int*)d_in[3];
  const int* ecol  = (const int*)d_in[4];
  const float* ev  = (const float*)d_in[5];
  float* out = (float*)d_out;

  char* p = (char*)d_ws;
  ushort_t* emb_a = (ushort_t*)p;  p += (size_t)Nn * Dd * 2;           // 6.4 MB
  ushort_t* emb_b = (ushort_t*)p;  p += (size_t)Nn * Dd * 2;           // 6.4 MB
  ushort_t* wbf   = (ushort_t*)p;  p += (size_t)2 * Rr * Dd * Dd * 2;  // 256 KB
  ushort_t* Z     = (ushort_t*)p;  p += (size_t)Nn * Rr * Dd * 2;      // 102.4 MB
  unsigned* ed    = (unsigned*)p;  p += (size_t)Rr * Ee * 4;           // 6.4 MB
  int* offs2      = (int*)p;       p += (size_t)(NB2 + 4) * 4;         // 3.2 MB
  int* cnt2       = (int*)p;       p += (size_t)NB2 * 4;               // 3.2 MB
  int* bsum       = (int*)p;       p += (size_t)SCAN_NBX * 4;

  hipMemsetAsync(cnt2, 0, (size_t)NB2 * 4, stream);
  pre_k<<<INIT_NB + CONVW_NB + HIST_NBX * Rr, 256, 0, stream>>>(
      x, ent, emb_a, rel, wbf, erow, cnt2);
  scan1_k<<<SCAN_NBX, 256, 0, stream>>>(cnt2, bsum);
  scan2_k<<<1, 1024, 0, stream>>>(bsum);
  scan3_k<<<SCAN_NBX, 256, 0, stream>>>(cnt2, bsum, offs2);
  scatter_k<<<dim3((Ee + 255) / 256, Rr), 256, 0, stream>>>(erow, ecol, ev, cnt2, ed);

  // layer 1
  gather3_k<<<(Nn + 3) / 4, 256, 0, stream>>>(emb_a, offs2, ed, Z);
  zgemm_k<<<(Nn / 16 + 3) / 4, 256, 0, stream>>>(Z, wbf, emb_b, nullptr, 0);
  // layer 2 (+ relu + L2 normalize fused)
  gather3_k<<<(Nn + 3) / 4, 256, 0, stream>>>(emb_b, offs2, ed, Z);
  zgemm_k<<<(Nn / 16 + 3) / 4, 256, 0, stream>>>(Z, wbf + (size_t)Rr * Dd * Dd,
                                                 nullptr, out, 1);
}

// Round 8
// 534.310 us; speedup vs baseline: 2.9174x; 1.2473x over previous
//
#include <hip/hip_runtime.h>

#define Nn 50000
#define Rr 16
#define Dd 64
#define Fin 128
#define Ee 100000
#define NB2 (Nn * Rr)  // 800000 (row,rel) bins

typedef __attribute__((ext_vector_type(8))) short short8;
typedef __attribute__((ext_vector_type(4))) float f32x4;
typedef unsigned short ushort_t;

__device__ inline ushort_t f2bf(float x) {
  union { float f; unsigned u; } v; v.f = x;
  unsigned u = v.u;
  return (ushort_t)((u + 0x7FFFu + ((u >> 16) & 1u)) >> 16);  // RNE
}
__device__ inline float bf2f(ushort_t h) {
  union { unsigned u; float f; } v; v.u = ((unsigned)h) << 16; return v.f;
}

// ---------------- fused pre: MFMA init_gemm + convw + hist ----------------
#define INIT_TILES 3125            // 50000/16
#define INIT_NB 782                // ceil(3125/4)
#define CONVW_NB 512               // 2*16*64*64 / 256
#define HIST_NBX 391               // ceil(100000/256)
__global__ __launch_bounds__(256) void pre_k(const float* __restrict__ x,
                                             const float* __restrict__ ent,
                                             ushort_t* __restrict__ emb0,
                                             const float* __restrict__ rel,
                                             ushort_t* __restrict__ wbf,
                                             const int* __restrict__ erow,
                                             int* __restrict__ cnt2) {
  int b = blockIdx.x;
  if (b < INIT_NB) {
    int wave = threadIdx.x >> 6, lane = threadIdx.x & 63;
    int nt = lane & 15, quad = lane >> 4;
    int tile = b * 4 + wave;
    if (tile >= INIT_TILES) return;
    const float* xr = x + ((long)tile * 16 + nt) * Fin + quad * 8;
    short8 afrag[4];
#pragma unroll
    for (int ks = 0; ks < 4; ++ks) {
      float4 p0 = *(const float4*)(xr + ks * 32);
      float4 p1 = *(const float4*)(xr + ks * 32 + 4);
      short8 a;
      a[0] = (short)f2bf(p0.x); a[1] = (short)f2bf(p0.y);
      a[2] = (short)f2bf(p0.z); a[3] = (short)f2bf(p0.w);
      a[4] = (short)f2bf(p1.x); a[5] = (short)f2bf(p1.y);
      a[6] = (short)f2bf(p1.z); a[7] = (short)f2bf(p1.w);
      afrag[ks] = a;
    }
    f32x4 acc[4];
#pragma unroll
    for (int dt = 0; dt < 4; ++dt) acc[dt] = (f32x4){0.f, 0.f, 0.f, 0.f};
#pragma unroll
    for (int ks = 0; ks < 4; ++ks) {
#pragma unroll
      for (int dt = 0; dt < 4; ++dt) {
        short8 bfr;
#pragma unroll
        for (int j = 0; j < 8; ++j)
          bfr[j] = (short)f2bf(ent[(unsigned)(ks * 32 + quad * 8 + j) * Dd + dt * 16 + nt]);
        acc[dt] = __builtin_amdgcn_mfma_f32_16x16x32_bf16(afrag[ks], bfr, acc[dt], 0, 0, 0);
      }
    }
#pragma unroll
    for (int dt = 0; dt < 4; ++dt)
#pragma unroll
      for (int reg = 0; reg < 4; ++reg) {
        int row = tile * 16 + quad * 4 + reg;
        emb0[(unsigned)row * Dd + dt * 16 + nt] = f2bf(acc[dt][reg]);
      }
  } else if (b < INIT_NB + CONVW_NB) {
    int i = (b - INIT_NB) * 256 + threadIdx.x;
    wbf[i] = f2bf(rel[i]);
  } else {
    int bb = b - INIT_NB - CONVW_NB;
    int r = bb / HIST_NBX;
    int e = (bb % HIST_NBX) * 256 + threadIdx.x;
    if (e < Ee) atomicAdd(&cnt2[erow[r * Ee + e] * Rr + r], 1);
  }
}

// ---------------- parallel scan over 800000 bins, 3 kernels ----------------
#define SCAN_NBX 3125  // 800000 / 256 exact
__global__ __launch_bounds__(256) void scan1_k(const int* __restrict__ cnt,
                                               int* __restrict__ bsum) {
  __shared__ int ls[256];
  int t = threadIdx.x;
  ls[t] = cnt[blockIdx.x * 256 + t];
  __syncthreads();
  for (int off = 128; off >= 1; off >>= 1) {
    if (t < off) ls[t] += ls[t + off];
    __syncthreads();
  }
  if (t == 0) bsum[blockIdx.x] = ls[0];
}

__global__ __launch_bounds__(1024) void scan2_k(int* __restrict__ bsum) {
  __shared__ int ls[1024];
  int t = threadIdx.x;
  int v[4], s = 0;
#pragma unroll
  for (int j = 0; j < 4; ++j) {
    int idx = t * 4 + j;
    v[j] = (idx < SCAN_NBX) ? bsum[idx] : 0;
    s += v[j];
  }
  ls[t] = s;
  __syncthreads();
  for (int off = 1; off < 1024; off <<= 1) {
    int x = (t >= off) ? ls[t - off] : 0;
    __syncthreads();
    ls[t] += x;
    __syncthreads();
  }
  int run = ls[t] - s;  // exclusive
#pragma unroll
  for (int j = 0; j < 4; ++j) {
    int idx = t * 4 + j;
    if (idx < SCAN_NBX) { bsum[idx] = run; run += v[j]; }
  }
}

__global__ __launch_bounds__(256) void scan3_k(int* __restrict__ cnt,
                                               const int* __restrict__ bsum,
                                               int* __restrict__ offs) {
  __shared__ int ls[256];
  int t = threadIdx.x, i = blockIdx.x * 256 + t;
  int v = cnt[i];
  ls[t] = v;
  __syncthreads();
  for (int off = 1; off < 256; off <<= 1) {
    int x = (t >= off) ? ls[t - off] : 0;
    __syncthreads();
    ls[t] += x;
    __syncthreads();
  }
  int excl = ls[t] - v + bsum[blockIdx.x];
  offs[i] = excl;
  cnt[i] = excl;  // becomes cursor
  if (i == NB2 - 1) offs[NB2] = Rr * Ee;
}

// ------- scatter into (row,rel)-sorted order; ed = (val_bf16<<16 | col) -----
__global__ __launch_bounds__(256) void scatter_k(const int* __restrict__ erow,
                                                 const int* __restrict__ ecol,
                                                 const float* __restrict__ ev,
                                                 int* __restrict__ cursor,
                                                 unsigned* __restrict__ ed) {
  int e = blockIdx.x * 256 + threadIdx.x;
  int r = blockIdx.y;
  if (e >= Ee) return;
  long idx = (long)r * Ee + e;
  int bin = erow[idx] * Rr + r;
  int pos = atomicAdd(&cursor[bin], 1);
  unsigned vb = f2bf(ev[idx]);
  ed[pos] = (vb << 16) | (unsigned)ecol[idx];
}

// ---------------- gather5: lane-parallel prefetch + selector-MFMA -----------
// Wave per row. Chunk of 32 edges: 1 coalesced ed load -> 32 independent emb
// loads (addrs via shfl, no mem dependence) staged d-major into wave-private
// LDS -> segmented sum over (row,rel) done by ONE 16x16x32 MFMA per d-tile
// with A = selector (val if slot in rel's segment else 0). No atomics, no
// barriers, no dynamic inner loops.
#define PITCH 40  // shorts; 80B rows: b64 writes & b128 reads at bank floor
__global__ __launch_bounds__(256) void gather5_k(const ushort_t* __restrict__ emb,
                                                 const int* __restrict__ offs2,
                                                 const unsigned* __restrict__ ed,
                                                 ushort_t* __restrict__ Z) {
  __shared__ ushort_t lds[4][Dd * PITCH];  // 4 x 5120B, wave-private
  const int wave = threadIdx.x >> 6, lane = threadIdx.x & 63;
  const int nt = lane & 15, quad = lane >> 4;
  const int row = blockIdx.x * 4 + wave;
  if (row >= Nn) return;
  ushort_t* lw = lds[wave];

  int off_l = (lane < 17) ? offs2[row * Rr + lane] : 0;
  const int base = __shfl(off_l, 0, 64);
  const int len  = __shfl(off_l, 16, 64) - base;
  const int rs_lo = __shfl(off_l, nt, 64) - base;      // rel=nt segment start
  const int rs_hi = __shfl(off_l, nt + 1, 64) - base;  // rel=nt segment end

  f32x4 acc[4];
#pragma unroll
  for (int dt = 0; dt < 4; ++dt) acc[dt] = (f32x4){0.f, 0.f, 0.f, 0.f};

  for (int c = 0; c < len; c += 32) {
    int p = c + (lane & 31);
    unsigned myed = (p < len) ? ed[base + p] : 0u;  // coalesced; garbage->col0,val0

    // phase A: stage 32 emb rows into LDS, d-major (2 batches of 16 loads)
#pragma unroll
    for (int h = 0; h < 2; ++h) {
      ushort_t y[16];
#pragma unroll
      for (int j = 0; j < 16; ++j) {
        unsigned q = (unsigned)__shfl((int)myed, h * 16 + j, 64);
        y[j] = emb[(q & 0xFFFFu) * 64u + lane];  // 16 independent 128B reads
      }
#pragma unroll
      for (int g = 0; g < 4; ++g) {
        unsigned lo = (unsigned)y[g * 4]     | ((unsigned)y[g * 4 + 1] << 16);
        unsigned hi = (unsigned)y[g * 4 + 2] | ((unsigned)y[g * 4 + 3] << 16);
        *(uint2*)(lw + lane * PITCH + h * 16 + g * 4) = make_uint2(lo, hi);
      }
    }

    // phase B: selector A-frag (branchless) + 4 MFMAs
    short8 afr;
#pragma unroll
    for (int j = 0; j < 8; ++j) {
      int slot = quad * 8 + j;
      unsigned q = (unsigned)__shfl((int)myed, slot, 64);
      int pos = c + slot;
      afr[j] = (pos >= rs_lo && pos < rs_hi) ? (short)(q >> 16) : (short)0;
    }
#pragma unroll
    for (int dt = 0; dt < 4; ++dt) {
      short8 bfr = *(const short8*)(lw + (dt * 16 + nt) * PITCH + quad * 8);
      acc[dt] = __builtin_amdgcn_mfma_f32_16x16x32_bf16(afr, bfr, acc[dt], 0, 0, 0);
    }
  }

  // D[m=quad*4+reg][n=dt*16+nt]: m=rel, n=d -> Z[row][rel][d]
  ushort_t* zrow = Z + (size_t)row * (Rr * Dd);
#pragma unroll
  for (int dt = 0; dt < 4; ++dt)
#pragma unroll
    for (int reg = 0; reg < 4; ++reg)
      zrow[(quad * 4 + reg) * Dd + dt * 16 + nt] = f2bf(acc[dt][reg]);
}

// ---------------- zgemm: out[row] = relu(sum_r Z[row][r] @ W_r^T) -----------
__global__ __launch_bounds__(256) void zgemm_k(const ushort_t* __restrict__ Z,
                                               const ushort_t* __restrict__ wl,
                                               ushort_t* __restrict__ embout,
                                               float* __restrict__ finout,
                                               int fin) {
  int wave = threadIdx.x >> 6, lane = threadIdx.x & 63;
  int nt = lane & 15, quad = lane >> 4;
  int tile = blockIdx.x * 4 + wave;
  if (tile >= Nn / 16) return;

  const ushort_t* za = Z + (size_t)(tile * 16 + nt) * (Rr * Dd) + quad * 8;
  f32x4 acc[4];
#pragma unroll
  for (int dt = 0; dt < 4; ++dt) acc[dt] = (f32x4){0.f, 0.f, 0.f, 0.f};

  for (int r = 0; r < Rr; ++r) {
    short8 a0 = *(const short8*)(za + r * Dd);
    short8 a1 = *(const short8*)(za + r * Dd + 32);
#pragma unroll
    for (int dt = 0; dt < 4; ++dt) {
      const ushort_t* bp = wl + ((unsigned)r * Dd + dt * 16 + nt) * Dd + quad * 8;
      short8 b0 = *(const short8*)(bp);
      short8 b1 = *(const short8*)(bp + 32);
      acc[dt] = __builtin_amdgcn_mfma_f32_16x16x32_bf16(a0, b0, acc[dt], 0, 0, 0);
      acc[dt] = __builtin_amdgcn_mfma_f32_16x16x32_bf16(a1, b1, acc[dt], 0, 0, 0);
    }
  }

  if (!fin) {
#pragma unroll
    for (int dt = 0; dt < 4; ++dt)
#pragma unroll
      for (int reg = 0; reg < 4; ++reg) {
        int row = tile * 16 + quad * 4 + reg;
        embout[(unsigned)row * 64u + dt * 16 + nt] = f2bf(fmaxf(acc[dt][reg], 0.f));
      }
  } else {
    float v[4][4];
#pragma unroll
    for (int dt = 0; dt < 4; ++dt)
#pragma unroll
      for (int reg = 0; reg < 4; ++reg) v[dt][reg] = fmaxf(acc[dt][reg], 0.f);
#pragma unroll
    for (int reg = 0; reg < 4; ++reg) {
      float ss = 0.f;
#pragma unroll
      for (int dt = 0; dt < 4; ++dt) ss = fmaf(v[dt][reg], v[dt][reg], ss);
#pragma unroll
      for (int off = 8; off >= 1; off >>= 1)
        ss += __shfl_xor(ss, off, 64);  // reduce over nt
      float sc = 1.f / fmaxf(sqrtf(ss), 1e-12f);
      int row = tile * 16 + quad * 4 + reg;
#pragma unroll
      for (int dt = 0; dt < 4; ++dt)
        finout[(unsigned)row * 64u + dt * 16 + nt] = v[dt][reg] * sc;
    }
  }
}

extern "C" void kernel_launch(void* const* d_in, const int* in_sizes, int n_in,
                              void* d_out, int out_size, void* d_ws, size_t ws_size,
                              hipStream_t stream) {
  const float* x   = (const float*)d_in[0];
  const float* ent = (const float*)d_in[1];
  const float* rel = (const float*)d_in[2];
  const int* erow  = (const int*)d_in[3];
  const int* ecol  = (const int*)d_in[4];
  const float* ev  = (const float*)d_in[5];
  float* out = (float*)d_out;

  char* p = (char*)d_ws;
  ushort_t* emb_a = (ushort_t*)p;  p += (size_t)Nn * Dd * 2;           // 6.4 MB
  ushort_t* emb_b = (ushort_t*)p;  p += (size_t)Nn * Dd * 2;           // 6.4 MB
  ushort_t* wbf   = (ushort_t*)p;  p += (size_t)2 * Rr * Dd * Dd * 2;  // 256 KB
  ushort_t* Z     = (ushort_t*)p;  p += (size_t)Nn * Rr * Dd * 2;      // 102.4 MB
  unsigned* ed    = (unsigned*)p;  p += (size_t)Rr * Ee * 4;           // 6.4 MB
  int* offs2      = (int*)p;       p += (size_t)(NB2 + 4) * 4;         // 3.2 MB
  int* cnt2       = (int*)p;       p += (size_t)NB2 * 4;               // 3.2 MB
  int* bsum       = (int*)p;       p += (size_t)SCAN_NBX * 4;

  hipMemsetAsync(cnt2, 0, (size_t)NB2 * 4, stream);
  pre_k<<<INIT_NB + CONVW_NB + HIST_NBX * Rr, 256, 0, stream>>>(
      x, ent, emb_a, rel, wbf, erow, cnt2);
  scan1_k<<<SCAN_NBX, 256, 0, stream>>>(cnt2, bsum);
  scan2_k<<<1, 1024, 0, stream>>>(bsum);
  scan3_k<<<SCAN_NBX, 256, 0, stream>>>(cnt2, bsum, offs2);
  scatter_k<<<dim3((Ee + 255) / 256, Rr), 256, 0, stream>>>(erow, ecol, ev, cnt2, ed);

  // layer 1
  gather5_k<<<(Nn + 3) / 4, 256, 0, stream>>>(emb_a, offs2, ed, Z);
  zgemm_k<<<(Nn / 16 + 3) / 4, 256, 0, stream>>>(Z, wbf, emb_b, nullptr, 0);
  // layer 2 (+ relu + L2 normalize fused)
  gather5_k<<<(Nn + 3) / 4, 256, 0, stream>>>(emb_b, offs2, ed, Z);
  zgemm_k<<<(Nn / 16 + 3) / 4, 256, 0, stream>>>(Z, wbf + (size_t)Rr * Dd * Dd,
                                                 nullptr, out, 1);
}